// Round 2
// baseline (266.604 us; speedup 1.0000x reference)
//
#include <hip/hip_runtime.h>
#include <hip/hip_bf16.h>

typedef float f32x4 __attribute__((ext_vector_type(4)));
typedef short bfx8 __attribute__((ext_vector_type(8)));   // 8 bf16 in 4 VGPRs

typedef const __attribute__((address_space(1))) void* gvp;
typedef __attribute__((address_space(3))) void* lvp;

static __device__ __forceinline__ unsigned short f2bf(float f) {
    return __builtin_bit_cast(unsigned short, __float2bfloat16(f));
}

static __device__ __forceinline__ bfx8 cvt8(f32x4 lo, f32x4 hi) {
    bfx8 r;
    r[0] = (short)f2bf(lo[0]); r[1] = (short)f2bf(lo[1]);
    r[2] = (short)f2bf(lo[2]); r[3] = (short)f2bf(lo[3]);
    r[4] = (short)f2bf(hi[0]); r[5] = (short)f2bf(hi[1]);
    r[6] = (short)f2bf(hi[2]); r[7] = (short)f2bf(hi[3]);
    return r;
}

// ---------------------------------------------------------------------------
// Kernel 0: cast + transpose weights into WcatT[768][768] bf16.
// Row n: n<256 -> Wq col n, 256..511 -> Wk, 512..767 -> Wv.
// ---------------------------------------------------------------------------
__global__ void prep_w(const float* __restrict__ Wk, const float* __restrict__ Wq,
                       const float* __restrict__ Wv, unsigned short* __restrict__ WT) {
    const int n = blockIdx.x;       // 0..767
    const int e = threadIdx.x;      // 0..767
    const int which = n >> 8;
    const int h = n & 255;
    const float* W = (which == 0) ? Wq : (which == 1) ? Wk : Wv;
    WT[(size_t)n * 768 + e] = f2bf(W[(size_t)e * 256 + h]);
}

// ---------------------------------------------------------------------------
// Kernel 1: QKV = X @ [Wq|Wk|Wv].  m97 structure: global_load_lds width=16
// for BOTH operands, A kept f32 in LDS (convert at fragment read).
//   bn 0..3 (Q,K): out [t][h];  bn 4..5 (V): operand-swapped MFMA -> out V'[h][t]
// 128x128 tile, 4 waves (2x2), BK=64, 12 K-steps, 16x16x32 bf16 MFMA.
// ---------------------------------------------------------------------------
__global__ __launch_bounds__(256) void qkv_gemm(const float* __restrict__ X,
                                                const unsigned short* __restrict__ WT,
                                                unsigned short* __restrict__ QKV) {
    __shared__ float          Abf[128][64];   // 32 KB, linear (global_load_lds dest)
    __shared__ unsigned short Bb[128][64];    // 16 KB, linear

    const int tid = threadIdx.x;
    const int bn = blockIdx.x;           // 0..5 (fast-varying: shares X tile in L2)
    const int bm = blockIdx.y;           // 0..511 (= batch)
    const int m0 = bm * 128;
    const int n0 = bn * 128;
    const int w = tid >> 6, lane = tid & 63;
    const int wr = w >> 1, wc = w & 1;
    const int lrow = lane & 15, lhi = lane >> 4;
    const bool vswap = (bn >= 4);

    f32x4 acc[4][4];
    const f32x4 zero = {0.f, 0.f, 0.f, 0.f};
#pragma unroll
    for (int i = 0; i < 4; ++i)
#pragma unroll
        for (int j = 0; j < 4; ++j) acc[i][j] = zero;

    for (int kt = 0; kt < 12; ++kt) {
        const int k0 = kt * 64;
        // ---- stage A (f32, 32KB): 8 x global_load_lds dwordx4 per thread-set
#pragma unroll
        for (int i = 0; i < 8; ++i) {
            const int f = i * 256 + tid;
            const int row = f >> 4, col = (f & 15) * 4;
            const float* g = X + (size_t)(m0 + row) * 768 + k0 + col;
            char* lp = (char*)&Abf[0][0] + i * 4096 + w * 1024;
            __builtin_amdgcn_global_load_lds((gvp)g, (lvp)lp, 16, 0, 0);
        }
        // ---- stage B (bf16, 16KB): 4 issues
#pragma unroll
        for (int i = 0; i < 4; ++i) {
            const int f = i * 256 + tid;
            const int row = f >> 3, col = (f & 7) * 8;
            const unsigned short* g = WT + (size_t)(n0 + row) * 768 + k0 + col;
            char* lp = (char*)&Bb[0][0] + i * 4096 + w * 1024;
            __builtin_amdgcn_global_load_lds((gvp)g, (lvp)lp, 16, 0, 0);
        }
        asm volatile("s_waitcnt vmcnt(0)" ::: "memory");
        __syncthreads();

#pragma unroll
        for (int kk = 0; kk < 2; ++kk) {
            const int kb = kk * 32 + lhi * 8;
            bfx8 a[4], bb4[4];
#pragma unroll
            for (int mi = 0; mi < 4; ++mi) {
                const f32x4* p = (const f32x4*)&Abf[wr * 64 + mi * 16 + lrow][kb];
                a[mi] = cvt8(p[0], p[1]);
            }
#pragma unroll
            for (int ni = 0; ni < 4; ++ni)
                bb4[ni] = *(const bfx8*)&Bb[wc * 64 + ni * 16 + lrow][kb];
            if (!vswap) {
#pragma unroll
                for (int mi = 0; mi < 4; ++mi)
#pragma unroll
                    for (int ni = 0; ni < 4; ++ni)
                        acc[mi][ni] = __builtin_amdgcn_mfma_f32_16x16x32_bf16(
                            a[mi], bb4[ni], acc[mi][ni], 0, 0, 0);
            } else {
                // V: swap operands so C's lane-fast dim = t (coalesced V'[h][t] store)
#pragma unroll
                for (int ni = 0; ni < 4; ++ni)
#pragma unroll
                    for (int mi = 0; mi < 4; ++mi)
                        acc[ni][mi] = __builtin_amdgcn_mfma_f32_16x16x32_bf16(
                            bb4[ni], a[mi], acc[ni][mi], 0, 0, 0);
            }
        }
        __syncthreads();
    }

    const int b = bm;
    if (!vswap) {
        const int which = bn >> 1;                         // 0=Q, 1=K
        const size_t base = ((size_t)(b * 3 + which)) << 15;
        const int hbase = (bn & 1) * 128;
#pragma unroll
        for (int mi = 0; mi < 4; ++mi)
#pragma unroll
            for (int ni = 0; ni < 4; ++ni) {
                const int t = wr * 64 + mi * 16 + lhi * 4;
                const int h = hbase + wc * 64 + ni * 16 + lrow;
#pragma unroll
                for (int j = 0; j < 4; ++j)
                    QKV[base + (size_t)(t + j) * 256 + h] = f2bf(acc[mi][ni][j]);
            }
    } else {
        const size_t base = ((size_t)(b * 3 + 2)) << 15;
#pragma unroll
        for (int ni = 0; ni < 4; ++ni)
#pragma unroll
            for (int mi = 0; mi < 4; ++mi) {
                const int h = (bn - 4) * 128 + wc * 64 + ni * 16 + lhi * 4;
                const int t = wr * 64 + mi * 16 + lrow;
#pragma unroll
                for (int j = 0; j < 4; ++j)
                    QKV[base + (size_t)(h + j) * 128 + t] = f2bf(acc[ni][mi][j]);
            }
    }
}

// ---------------------------------------------------------------------------
// Kernel 2: per-batch causal attention (unchanged from round 0 — passed).
// ---------------------------------------------------------------------------
__global__ __launch_bounds__(512) void attn(const unsigned short* __restrict__ QKV,
                                            float* __restrict__ Out) {
    __shared__ unsigned short Kl[128][264];   // 67584 B
    __shared__ unsigned short Vt[256][136];   // 69632 B

    const int b = blockIdx.x;
    const int tid = threadIdx.x;
    const int w = tid >> 6, lane = tid & 63;
    const int lrow = lane & 15, lhi = lane >> 4;

    const unsigned short* Qb = QKV + ((size_t)(b * 3 + 0) << 15);
    const unsigned short* Kb = QKV + ((size_t)(b * 3 + 1) << 15);
    const unsigned short* Vb = QKV + ((size_t)(b * 3 + 2) << 15);

    const int t0 = w * 16;
    bfx8 aq[8];
#pragma unroll
    for (int kk = 0; kk < 8; ++kk)
        aq[kk] = *(const bfx8*)(Qb + (size_t)(t0 + lrow) * 256 + kk * 32 + lhi * 8);

#pragma unroll
    for (int i = 0; i < 8; ++i) {
        int f = i * 512 + tid;
        {
            int row = f >> 5, c = (f & 31) * 8;
            *(bfx8*)&Kl[row][c] = *(const bfx8*)(Kb + (size_t)row * 256 + c);
        }
        {
            int row = f >> 4, c = (f & 15) * 8;
            *(bfx8*)&Vt[row][c] = *(const bfx8*)(Vb + (size_t)row * 128 + c);
        }
    }
    __syncthreads();

    f32x4 sacc[8];
    const f32x4 zero = {0.f, 0.f, 0.f, 0.f};
#pragma unroll
    for (int sj = 0; sj < 8; ++sj) sacc[sj] = zero;
#pragma unroll
    for (int kk = 0; kk < 8; ++kk) {
        const int kb = kk * 32 + lhi * 8;
#pragma unroll
        for (int sj = 0; sj < 8; ++sj) {
            bfx8 bk = *(const bfx8*)&Kl[sj * 16 + lrow][kb];
            sacc[sj] = __builtin_amdgcn_mfma_f32_16x16x32_bf16(aq[kk], bk, sacc[sj], 0, 0, 0);
        }
    }

    const float scale = 0.03608439182435161f;   // 1/sqrt(768)
    float inv[4];
#pragma unroll
    for (int j = 0; j < 4; ++j) {
        const int t = t0 + lhi * 4 + j;
        float m = -1e30f;
#pragma unroll
        for (int sj = 0; sj < 8; ++sj) {
            int s = sj * 16 + lrow;
            float vv = sacc[sj][j] * scale;
            vv = (s <= t) ? vv : -1e30f;
            sacc[sj][j] = vv;
            m = fmaxf(m, vv);
        }
#pragma unroll
        for (int d = 1; d < 16; d <<= 1) m = fmaxf(m, __shfl_xor(m, d));
        float sum = 0.f;
#pragma unroll
        for (int sj = 0; sj < 8; ++sj) {
            float e = __expf(sacc[sj][j] - m);
            sacc[sj][j] = e;
            sum += e;
        }
#pragma unroll
        for (int d = 1; d < 16; d <<= 1) sum += __shfl_xor(sum, d);
        inv[j] = 1.0f / sum;
    }

    __syncthreads();

    unsigned short* Pl = &Kl[0][0] + (size_t)w * (16 * 136);
#pragma unroll
    for (int sj = 0; sj < 8; ++sj)
#pragma unroll
        for (int j = 0; j < 4; ++j)
            Pl[(lhi * 4 + j) * 136 + sj * 16 + lrow] = f2bf(sacc[sj][j] * inv[j]);

    bfx8 pa[4];
#pragma unroll
    for (int kk = 0; kk < 4; ++kk)
        pa[kk] = *(const bfx8*)(Pl + lrow * 136 + kk * 32 + lhi * 8);

    f32x4 oacc[16];
#pragma unroll
    for (int ni = 0; ni < 16; ++ni) oacc[ni] = zero;
#pragma unroll
    for (int ni = 0; ni < 16; ++ni) {
#pragma unroll
        for (int kk = 0; kk < 4; ++kk) {
            bfx8 bv = *(const bfx8*)&Vt[ni * 16 + lrow][kk * 32 + lhi * 8];
            oacc[ni] = __builtin_amdgcn_mfma_f32_16x16x32_bf16(pa[kk], bv, oacc[ni], 0, 0, 0);
        }
    }

    float* Ob = Out + (size_t)b * 128 * 256;
#pragma unroll
    for (int ni = 0; ni < 16; ++ni) {
#pragma unroll
        for (int j = 0; j < 4; ++j) {
            const int t = t0 + lhi * 4 + j;
            const int h = ni * 16 + lrow;
            Ob[(size_t)t * 256 + h] = oacc[ni][j];
        }
    }
}

// ---------------------------------------------------------------------------
extern "C" void kernel_launch(void* const* d_in, const int* in_sizes, int n_in,
                              void* d_out, int out_size, void* d_ws, size_t ws_size,
                              hipStream_t stream) {
    (void)in_sizes; (void)n_in; (void)out_size; (void)ws_size;
    const float* X  = (const float*)d_in[0];   // res_stream [512,128,768]
    const float* Wk = (const float*)d_in[1];   // [768,256]
    const float* Wq = (const float*)d_in[2];
    const float* Wv = (const float*)d_in[3];

    unsigned short* WT  = (unsigned short*)d_ws;          // 768*768 bf16
    unsigned short* QKV = WT + (size_t)768 * 768;         // 512*3*32768 bf16
    float* Out = (float*)d_out;

    prep_w<<<768, 768, 0, stream>>>(Wk, Wq, Wv, WT);
    qkv_gemm<<<dim3(6, 512), 256, 0, stream>>>(X, WT, QKV);
    attn<<<512, 512, 0, stream>>>(QKV, Out);
}

// Round 3
// 194.484 us; speedup vs baseline: 1.3708x; 1.3708x over previous
//
#include <hip/hip_runtime.h>
#include <hip/hip_bf16.h>

typedef float f32x4 __attribute__((ext_vector_type(4)));
typedef short bfx8 __attribute__((ext_vector_type(8)));   // 8 bf16 in 4 VGPRs

typedef const __attribute__((address_space(1))) void* gvp;
typedef __attribute__((address_space(3))) void* lvp;

static __device__ __forceinline__ unsigned short f2bf(float f) {
    return __builtin_bit_cast(unsigned short, __float2bfloat16(f));
}

static __device__ __forceinline__ bfx8 cvt8(f32x4 lo, f32x4 hi) {
    bfx8 r;
    r[0] = (short)f2bf(lo[0]); r[1] = (short)f2bf(lo[1]);
    r[2] = (short)f2bf(lo[2]); r[3] = (short)f2bf(lo[3]);
    r[4] = (short)f2bf(hi[0]); r[5] = (short)f2bf(hi[1]);
    r[6] = (short)f2bf(hi[2]); r[7] = (short)f2bf(hi[3]);
    return r;
}

// ---------------------------------------------------------------------------
// Kernel 0: cast + transpose weights into WcatT[768][768] bf16.
// ---------------------------------------------------------------------------
__global__ void prep_w(const float* __restrict__ Wk, const float* __restrict__ Wq,
                       const float* __restrict__ Wv, unsigned short* __restrict__ WT) {
    const int n = blockIdx.x;       // 0..767
    const int e = threadIdx.x;      // 0..767
    const int which = n >> 8;
    const int h = n & 255;
    const float* W = (which == 0) ? Wq : (which == 1) ? Wk : Wv;
    WT[(size_t)n * 768 + e] = f2bf(W[(size_t)e * 256 + h]);
}

// ---------------------------------------------------------------------------
// Kernel 1: QKV = X @ [Wq|Wk|Wv]. global_load_lds staging (linear LDS dest),
// bank-conflict-free via pre-swizzled global SOURCE + swizzled ds_read
// (byte_in_row ^= (row&7)<<4). XCD-remapped 1D grid: the 6 n-blocks sharing
// an X tile run consecutively on the SAME XCD (L2 reuse).
//   bn 0..3 (Q,K): out [t][h];  bn 4..5 (V): operand-swapped -> out V'[h][t]
// ---------------------------------------------------------------------------
__global__ __launch_bounds__(256) void qkv_gemm(const float* __restrict__ X,
                                                const unsigned short* __restrict__ WT,
                                                unsigned short* __restrict__ QKV) {
    __shared__ float          Abf[128][64];   // 32 KB, 256B rows
    __shared__ unsigned short Bb[128][64];    // 16 KB, 128B rows

    const int tid = threadIdx.x;
    const int bid = blockIdx.x;                    // 0..3071
    const int l   = (bid & 7) * 384 + (bid >> 3);  // bijective XCD remap
    const int bn  = l % 6;
    const int bm  = l / 6;
    const int m0 = bm * 128;
    const int n0 = bn * 128;
    const int w = tid >> 6, lane = tid & 63;
    const int wr = w >> 1, wc = w & 1;
    const int lrow = lane & 15, lhi = lane >> 4;
    const bool vswap = (bn >= 4);

    f32x4 acc[4][4];
    const f32x4 zero = {0.f, 0.f, 0.f, 0.f};
#pragma unroll
    for (int i = 0; i < 4; ++i)
#pragma unroll
        for (int j = 0; j < 4; ++j) acc[i][j] = zero;

    for (int kt = 0; kt < 12; ++kt) {
        const int k0 = kt * 64;
        // ---- stage A (f32, 32KB): linear LDS dest, swizzled global source
#pragma unroll
        for (int i = 0; i < 8; ++i) {
            const int f = i * 256 + tid;
            const int row = f >> 4;
            const int cb  = (f & 15) * 16;               // byte-in-row (256B rows)
            const int cbs = cb ^ ((row & 7) << 4);       // inverse swizzle on src
            const float* g = X + (size_t)(m0 + row) * 768 + k0 + (cbs >> 2);
            char* lp = (char*)&Abf[0][0] + i * 4096 + w * 1024;
            __builtin_amdgcn_global_load_lds((gvp)g, (lvp)lp, 16, 0, 0);
        }
        // ---- stage B (bf16, 16KB)
#pragma unroll
        for (int i = 0; i < 4; ++i) {
            const int f = i * 256 + tid;
            const int row = f >> 3;
            const int cb  = (f & 7) * 16;                // byte-in-row (128B rows)
            const int cbs = cb ^ ((row & 7) << 4);
            const unsigned short* g = WT + (size_t)(n0 + row) * 768 + k0 + (cbs >> 1);
            char* lp = (char*)&Bb[0][0] + i * 4096 + w * 1024;
            __builtin_amdgcn_global_load_lds((gvp)g, (lvp)lp, 16, 0, 0);
        }
        asm volatile("s_waitcnt vmcnt(0)" ::: "memory");
        __syncthreads();

#pragma unroll
        for (int kk = 0; kk < 2; ++kk) {
            const int kb = kk * 32 + lhi * 8;            // f32/bf16 element col
            bfx8 a[4], bb4[4];
#pragma unroll
            for (int mi = 0; mi < 4; ++mi) {
                const int arow = wr * 64 + mi * 16 + lrow;
                const int s = (arow & 7) << 4;
                const char* ab = (const char*)&Abf[arow][0];
                f32x4 lo = *(const f32x4*)(ab + (((kb << 2))      ^ s));
                f32x4 hi = *(const f32x4*)(ab + (((kb << 2) + 16) ^ s));
                a[mi] = cvt8(lo, hi);
            }
#pragma unroll
            for (int ni = 0; ni < 4; ++ni) {
                const int brow = wc * 64 + ni * 16 + lrow;
                const int s = (brow & 7) << 4;
                const char* bb = (const char*)&Bb[brow][0];
                bb4[ni] = *(const bfx8*)(bb + ((kb << 1) ^ s));
            }
            if (!vswap) {
#pragma unroll
                for (int mi = 0; mi < 4; ++mi)
#pragma unroll
                    for (int ni = 0; ni < 4; ++ni)
                        acc[mi][ni] = __builtin_amdgcn_mfma_f32_16x16x32_bf16(
                            a[mi], bb4[ni], acc[mi][ni], 0, 0, 0);
            } else {
#pragma unroll
                for (int ni = 0; ni < 4; ++ni)
#pragma unroll
                    for (int mi = 0; mi < 4; ++mi)
                        acc[ni][mi] = __builtin_amdgcn_mfma_f32_16x16x32_bf16(
                            bb4[ni], a[mi], acc[ni][mi], 0, 0, 0);
            }
        }
        __syncthreads();
    }

    const int b = bm;
    if (!vswap) {
        const int which = bn >> 1;                         // 0=Q, 1=K
        const size_t base = ((size_t)(b * 3 + which)) << 15;
        const int hbase = (bn & 1) * 128;
#pragma unroll
        for (int mi = 0; mi < 4; ++mi)
#pragma unroll
            for (int ni = 0; ni < 4; ++ni) {
                const int t = wr * 64 + mi * 16 + lhi * 4;
                const int h = hbase + wc * 64 + ni * 16 + lrow;
#pragma unroll
                for (int j = 0; j < 4; ++j)
                    QKV[base + (size_t)(t + j) * 256 + h] = f2bf(acc[mi][ni][j]);
            }
    } else {
        const size_t base = ((size_t)(b * 3 + 2)) << 15;
#pragma unroll
        for (int ni = 0; ni < 4; ++ni)
#pragma unroll
            for (int mi = 0; mi < 4; ++mi) {
                const int h = (bn - 4) * 128 + wc * 64 + ni * 16 + lhi * 4;
                const int t = wr * 64 + mi * 16 + lrow;
#pragma unroll
                for (int j = 0; j < 4; ++j)
                    QKV[base + (size_t)(h + j) * 128 + t] = f2bf(acc[ni][mi][j]);
            }
    }
}

// ---------------------------------------------------------------------------
// Kernel 2: per-batch causal attention (unchanged — passing, ~23µs).
// ---------------------------------------------------------------------------
__global__ __launch_bounds__(512) void attn(const unsigned short* __restrict__ QKV,
                                            float* __restrict__ Out) {
    __shared__ unsigned short Kl[128][264];
    __shared__ unsigned short Vt[256][136];

    const int b = blockIdx.x;
    const int tid = threadIdx.x;
    const int w = tid >> 6, lane = tid & 63;
    const int lrow = lane & 15, lhi = lane >> 4;

    const unsigned short* Qb = QKV + ((size_t)(b * 3 + 0) << 15);
    const unsigned short* Kb = QKV + ((size_t)(b * 3 + 1) << 15);
    const unsigned short* Vb = QKV + ((size_t)(b * 3 + 2) << 15);

    const int t0 = w * 16;
    bfx8 aq[8];
#pragma unroll
    for (int kk = 0; kk < 8; ++kk)
        aq[kk] = *(const bfx8*)(Qb + (size_t)(t0 + lrow) * 256 + kk * 32 + lhi * 8);

#pragma unroll
    for (int i = 0; i < 8; ++i) {
        int f = i * 512 + tid;
        {
            int row = f >> 5, c = (f & 31) * 8;
            *(bfx8*)&Kl[row][c] = *(const bfx8*)(Kb + (size_t)row * 256 + c);
        }
        {
            int row = f >> 4, c = (f & 15) * 8;
            *(bfx8*)&Vt[row][c] = *(const bfx8*)(Vb + (size_t)row * 128 + c);
        }
    }
    __syncthreads();

    f32x4 sacc[8];
    const f32x4 zero = {0.f, 0.f, 0.f, 0.f};
#pragma unroll
    for (int sj = 0; sj < 8; ++sj) sacc[sj] = zero;
#pragma unroll
    for (int kk = 0; kk < 8; ++kk) {
        const int kb = kk * 32 + lhi * 8;
#pragma unroll
        for (int sj = 0; sj < 8; ++sj) {
            bfx8 bk = *(const bfx8*)&Kl[sj * 16 + lrow][kb];
            sacc[sj] = __builtin_amdgcn_mfma_f32_16x16x32_bf16(aq[kk], bk, sacc[sj], 0, 0, 0);
        }
    }

    const float scale = 0.03608439182435161f;   // 1/sqrt(768)
    float inv[4];
#pragma unroll
    for (int j = 0; j < 4; ++j) {
        const int t = t0 + lhi * 4 + j;
        float m = -1e30f;
#pragma unroll
        for (int sj = 0; sj < 8; ++sj) {
            int s = sj * 16 + lrow;
            float vv = sacc[sj][j] * scale;
            vv = (s <= t) ? vv : -1e30f;
            sacc[sj][j] = vv;
            m = fmaxf(m, vv);
        }
#pragma unroll
        for (int d = 1; d < 16; d <<= 1) m = fmaxf(m, __shfl_xor(m, d));
        float sum = 0.f;
#pragma unroll
        for (int sj = 0; sj < 8; ++sj) {
            float e = __expf(sacc[sj][j] - m);
            sacc[sj][j] = e;
            sum += e;
        }
#pragma unroll
        for (int d = 1; d < 16; d <<= 1) sum += __shfl_xor(sum, d);
        inv[j] = 1.0f / sum;
    }

    __syncthreads();

    unsigned short* Pl = &Kl[0][0] + (size_t)w * (16 * 136);
#pragma unroll
    for (int sj = 0; sj < 8; ++sj)
#pragma unroll
        for (int j = 0; j < 4; ++j)
            Pl[(lhi * 4 + j) * 136 + sj * 16 + lrow] = f2bf(sacc[sj][j] * inv[j]);

    bfx8 pa[4];
#pragma unroll
    for (int kk = 0; kk < 4; ++kk)
        pa[kk] = *(const bfx8*)(Pl + lrow * 136 + kk * 32 + lhi * 8);

    f32x4 oacc[16];
#pragma unroll
    for (int ni = 0; ni < 16; ++ni) oacc[ni] = zero;
#pragma unroll
    for (int ni = 0; ni < 16; ++ni) {
#pragma unroll
        for (int kk = 0; kk < 4; ++kk) {
            bfx8 bv = *(const bfx8*)&Vt[ni * 16 + lrow][kk * 32 + lhi * 8];
            oacc[ni] = __builtin_amdgcn_mfma_f32_16x16x32_bf16(pa[kk], bv, oacc[ni], 0, 0, 0);
        }
    }

    float* Ob = Out + (size_t)b * 128 * 256;
#pragma unroll
    for (int ni = 0; ni < 16; ++ni) {
#pragma unroll
        for (int j = 0; j < 4; ++j) {
            const int t = t0 + lhi * 4 + j;
            const int h = ni * 16 + lrow;
            Ob[(size_t)t * 256 + h] = oacc[ni][j];
        }
    }
}

// ---------------------------------------------------------------------------
extern "C" void kernel_launch(void* const* d_in, const int* in_sizes, int n_in,
                              void* d_out, int out_size, void* d_ws, size_t ws_size,
                              hipStream_t stream) {
    (void)in_sizes; (void)n_in; (void)out_size; (void)ws_size;
    const float* X  = (const float*)d_in[0];   // res_stream [512,128,768]
    const float* Wk = (const float*)d_in[1];   // [768,256]
    const float* Wq = (const float*)d_in[2];
    const float* Wv = (const float*)d_in[3];

    unsigned short* WT  = (unsigned short*)d_ws;          // 768*768 bf16
    unsigned short* QKV = WT + (size_t)768 * 768;         // 512*3*32768 bf16
    float* Out = (float*)d_out;

    prep_w<<<768, 768, 0, stream>>>(Wk, Wq, Wv, WT);
    qkv_gemm<<<3072, 256, 0, stream>>>(X, WT, QKV);
    attn<<<512, 512, 0, stream>>>(QKV, Out);
}